// Round 1
// baseline (432.854 us; speedup 1.0000x reference)
//
#include <hip/hip_runtime.h>

#define N_IN  16384
#define N_OUT 16384
#define KSZ   9
#define BB    2
#define CIN   32
#define COUT  32
#define BC    64   // BB*CIN

// ---------------------------------------------------------------------------
// Kernel 1: xq[in][bc] = x[bc][in] * qw[in]   (transpose + quadrature scale)
// 64x64 tile via LDS, both sides coalesced.
__global__ void k_xq(const float* __restrict__ x, const float* __restrict__ qw,
                     float* __restrict__ xq) {
    __shared__ float tile[64 * 65];
    const int in0 = blockIdx.x * 64;
    const int tid = threadIdx.x;
#pragma unroll
    for (int i = 0; i < 16; ++i) {
        int idx = tid + i * 256;
        int bcl = idx >> 6, inl = idx & 63;
        tile[bcl * 65 + inl] = x[bcl * N_IN + in0 + inl];
    }
    __syncthreads();
#pragma unroll
    for (int i = 0; i < 16; ++i) {
        int idx = tid + i * 256;
        int inl = idx >> 6, bcl = idx & 63;
        xq[(size_t)(in0 + inl) * BC + bcl] = tile[bcl * 65 + inl] * qw[in0 + inl];
    }
}

// ---------------------------------------------------------------------------
// Kernel 2: scatter-accumulate. One wave per sparse entry (grid-stride).
// lane = bc. 64 coalesced gather floats + 64 coalesced atomics per entry.
__global__ void k_scatter(const float* __restrict__ xq, const float* __restrict__ vals,
                          const int* __restrict__ ik, const int* __restrict__ io,
                          const int* __restrict__ ii, float* __restrict__ xk, int nnz) {
    const int lane = threadIdx.x & 63;
    const int wid  = (blockIdx.x * blockDim.x + threadIdx.x) >> 6;
    const int nw   = (gridDim.x * blockDim.x) >> 6;
    for (int e = wid; e < nnz; e += nw) {
        const int   k  = ik[e];
        const int   o  = io[e];
        const int   in = ii[e];
        const float v  = vals[e];
        const float c  = xq[(size_t)in * BC + lane] * v;
        atomicAdd(&xk[((size_t)k * N_OUT + o) * BC + lane], c);
    }
}

// ---------------------------------------------------------------------------
// Kernel 3: out[b][o][n] = sum_{k,c} xk[k][n][b*32+c] * w[o][c][k] + bias[o]
// Block handles TN=16 n-values; LDS-staged xk tile (pad 65) + weight (pad 289).
#define TN 16
__global__ void k_out(const float* __restrict__ xk, const float* __restrict__ w,
                      const float* __restrict__ bias, float* __restrict__ out) {
    __shared__ float sxk[KSZ * TN * 65];   // [k][nl][bc], bc-stride 65
    __shared__ float sw[COUT * 289];       // [o][c*9+k], o-stride 289
    const int tid = threadIdx.x;
    const int n0  = blockIdx.x * TN;

    for (int i = tid; i < COUT * CIN * KSZ; i += 256) {
        int o = i / (CIN * KSZ);
        int r = i - o * (CIN * KSZ);
        sw[o * 289 + r] = w[i];
    }
    for (int i = tid; i < KSZ * TN * BC; i += 256) {
        int k = i / (TN * BC);
        int r = i - k * (TN * BC);
        int nl = r >> 6, bc = r & 63;
        sxk[(k * TN + nl) * 65 + bc] = xk[((size_t)k * N_OUT + n0 + nl) * BC + bc];
    }
    __syncthreads();

    const int nl = tid & 15;
    const int og = tid >> 4;   // 0..15 ; o in {og, og+16}
    float a00 = 0.f, a01 = 0.f, a10 = 0.f, a11 = 0.f;
    for (int k = 0; k < KSZ; ++k) {
        const float* xr = &sxk[(k * TN + nl) * 65];
#pragma unroll
        for (int c = 0; c < CIN; ++c) {
            float x0 = xr[c];
            float x1 = xr[32 + c];
            float w0 = sw[og * 289 + c * 9 + k];
            float w1 = sw[(og + 16) * 289 + c * 9 + k];
            a00 += x0 * w0; a01 += x0 * w1;
            a10 += x1 * w0; a11 += x1 * w1;
        }
    }
    const float b0 = bias[og], b1 = bias[og + 16];
    out[(size_t)(0 * COUT + og) * N_OUT + n0 + nl]      = a00 + b0;
    out[(size_t)(0 * COUT + og + 16) * N_OUT + n0 + nl] = a01 + b1;
    out[(size_t)(1 * COUT + og) * N_OUT + n0 + nl]      = a10 + b0;
    out[(size_t)(1 * COUT + og + 16) * N_OUT + n0 + nl] = a11 + b1;
}

// ---------------------------------------------------------------------------
extern "C" void kernel_launch(void* const* d_in, const int* in_sizes, int n_in,
                              void* d_out, int out_size, void* d_ws, size_t ws_size,
                              hipStream_t stream) {
    const float* x    = (const float*)d_in[0];
    const float* qw   = (const float*)d_in[1];
    const float* vals = (const float*)d_in[2];
    const float* w    = (const float*)d_in[3];
    const float* bias = (const float*)d_in[4];
    const int*   ik   = (const int*)d_in[5];
    const int*   io   = (const int*)d_in[6];
    const int*   ii   = (const int*)d_in[7];
    const int    nnz  = in_sizes[2];

    float* xq = (float*)d_ws;                         // N_IN*64 floats  (4 MB)
    float* xk = xq + (size_t)N_IN * BC;               // KSZ*N_OUT*64 floats (37.7 MB)

    hipMemsetAsync(xk, 0, (size_t)KSZ * N_OUT * BC * sizeof(float), stream);
    k_xq<<<N_IN / 64, 256, 0, stream>>>(x, qw, xq);
    k_scatter<<<8192, 256, 0, stream>>>(xq, vals, ik, io, ii, xk, nnz);
    k_out<<<N_OUT / TN, 256, 0, stream>>>(xk, w, bias, (float*)d_out);
}